// Round 1
// 639.936 us; speedup vs baseline: 1.0058x; 1.0058x over previous
//
#include <hip/hip_runtime.h>
#include <math.h>

#define EPS 1e-5f
#define INV_N (1.0f / 1024.0f)

// out layout: prob[1024] @0, o1[1024*300] @1024, o2 @308224
// All GEMMs run as fp16-input MFMA (fp32 accumulate). K and N padded to
// multiples of 32/64 with zero fill so the MFMA K-loop needs no masking.
// This revision: 7 dispatches (was 10). BN+ReLU+cvt fused into the A-staging
// of the following GEMM; weight-convert fused into the gather dispatch;
// GEMM K-loop double-buffered with 2-deep register prefetch (1 sync/iter).

typedef _Float16 f16x8 __attribute__((ext_vector_type(8)));
typedef float f32x4 __attribute__((ext_vector_type(4)));

__device__ __forceinline__ _Float16 f2h(float f) { return (_Float16)f; }

static const int STATS_TOTAL = 3400;

// ---------------------------------------------------------------------------
// K1: fused. Blocks 0..2047: embedding gather + sum-pool -> xb (f16, K padded
// 300->320); block 0 also zeroes the stat buffers. Blocks 2048..3363: weight
// f16 conversion (4 elements/thread, 1316 blocks * 512 = 673792 elements).
// ---------------------------------------------------------------------------
__global__ __launch_bounds__(128) void gather_wcvt_kernel(
    const int* __restrict__ langs1, const int* __restrict__ sents1,
    const int* __restrict__ langs2, const int* __restrict__ sents2,
    const float* __restrict__ tables, _Float16* __restrict__ xb,
    float* __restrict__ stats,
    const float* __restrict__ w1, const float* __restrict__ w2,
    const float* __restrict__ w3, const float* __restrict__ w4,
    _Float16* __restrict__ w1b, _Float16* __restrict__ w2b,
    _Float16* __restrict__ w3b, _Float16* __restrict__ w4b)
{
    int bid = blockIdx.x, t = threadIdx.x;
    if (bid >= 2048) {
        int i0 = (bid - 2048) * 512 + t;
        #pragma unroll
        for (int u = 0; u < 4; u++) {
            int i = i0 + u * 128;
            if (i < 102400) {
                int r = i / 320, c = i - r * 320;
                w1b[i] = (r < 300 && c < 300) ? f2h(w1[r * 300 + c]) : (_Float16)0.f;
            } else if (i < 204800) {
                int j = i - 102400; int r = j / 320, c = j - r * 320;
                w2b[j] = (r < 300 && c < 300) ? f2h(w2[r * 300 + c]) : (_Float16)0.f;
            } else if (i < 620544) {
                int j = i - 204800; int r = j / 928, c = j - r * 928;
                w3b[j] = (r < 400 && c < 901) ? f2h(w3[r * 901 + c]) : (_Float16)0.f;
            } else if (i < 673792) {
                int j = i - 620544; int r = j / 416, c = j - r * 416;
                w4b[j] = (r < 100 && c < 400) ? f2h(w4[r * 400 + c]) : (_Float16)0.f;
            }
        }
        return;
    }
    if (bid == 0) {
        for (int i = t; i < STATS_TOTAL; i += 128) stats[i] = 0.f;
    }
    int side = bid >> 10, b = bid & 1023;
    const int* langs = side ? langs2 : langs1;
    const int* sents = side ? sents2 : sents1;
    __shared__ int toks[50];
    if (t < 50) toks[t] = sents[b * 50 + t];
    __syncthreads();
    const float* base = tables + (size_t)langs[b] * (200000ull * 300ull);
    float a0 = 0.f, a1 = 0.f, a2 = 0.f;
    #pragma unroll 5
    for (int s = 0; s < 50; s++) {
        const float* row = base + (size_t)toks[s] * 300;
        a0 += row[t];
        a1 += row[t + 128];
        if (t < 44) a2 += row[t + 256];
    }
    _Float16* xr = xb + (size_t)bid * 320;
    xr[t] = f2h(a0);
    xr[t + 128] = f2h(a1);
    if (t < 64) xr[t + 256] = (t < 44) ? f2h(a2) : (_Float16)0.f;
}

// ---------------------------------------------------------------------------
// MFMA GEMM (f16 A): C[M][N](fp32) = A[M][Kp](f16) @ W[N][Kp](f16)^T + bias.
// 64x64 block tile, 256 thr = 4 waves (2x2), each wave 32x32 via 2x2
// 16x16x32 frags. LDS seg-major [4 segs][64 rows][8 f16] per operand,
// double buffered; global loads prefetched 2 iterations ahead.
// Column sums/sumsqs of (C+bias) atomically accumulated into sSum/sSq
// (side 1 for rows >= 1024 when twoSided).
// ---------------------------------------------------------------------------
__global__ __launch_bounds__(256) void gemm_f16(
    const _Float16* __restrict__ A, const _Float16* __restrict__ W, int ldk,
    const float* __restrict__ bias, float* __restrict__ C, int ldc,
    int N, int kIters, float* __restrict__ sSum, float* __restrict__ sSq,
    int twoSided)
{
    __shared__ __align__(16) _Float16 lsA[2][2048];
    __shared__ __align__(16) _Float16 lsW[2][2048];
    int tid = threadIdx.x;
    int r0 = blockIdx.x * 64, c0 = blockIdx.y * 64;
    int lane = tid & 63;
    int wave = tid >> 6;
    int waveR = wave & 1, waveC = wave >> 1;
    int q = lane >> 4, m = lane & 15;

    int srow = tid >> 2, sseg = tid & 3;
    const _Float16* gA = A + (size_t)(r0 + srow) * ldk + sseg * 8;
    const _Float16* gW = W + (size_t)(c0 + srow) * ldk + sseg * 8;
    int stOff = sseg * 512 + srow * 8;

    int aoff0 = q * 512 + (waveR * 32 + m) * 8;
    int aoff1 = aoff0 + 128;      // +16 rows
    int boff0 = q * 512 + (waveC * 32 + m) * 8;
    int boff1 = boff0 + 128;

    f32x4 acc00 = {0.f,0.f,0.f,0.f}, acc01 = {0.f,0.f,0.f,0.f};
    f32x4 acc10 = {0.f,0.f,0.f,0.f}, acc11 = {0.f,0.f,0.f,0.f};

    // prologue: stage kt=0, prefetch kt=1
    uint4 va = *(const uint4*)gA;
    uint4 vw = *(const uint4*)gW;
    gA += 32; gW += 32;
    *(uint4*)&lsA[0][stOff] = va;
    *(uint4*)&lsW[0][stOff] = vw;
    if (kIters > 1) {
        va = *(const uint4*)gA; vw = *(const uint4*)gW;
        gA += 32; gW += 32;
    }
    __syncthreads();

    int cur = 0;
    for (int kt = 0; kt < kIters; kt++) {
        f16x8 a0 = *(const f16x8*)&lsA[cur][aoff0];
        f16x8 a1 = *(const f16x8*)&lsA[cur][aoff1];
        f16x8 b0 = *(const f16x8*)&lsW[cur][boff0];
        f16x8 b1 = *(const f16x8*)&lsW[cur][boff1];
        acc00 = __builtin_amdgcn_mfma_f32_16x16x32_f16(a0, b0, acc00, 0, 0, 0);
        acc01 = __builtin_amdgcn_mfma_f32_16x16x32_f16(a0, b1, acc01, 0, 0, 0);
        acc10 = __builtin_amdgcn_mfma_f32_16x16x32_f16(a1, b0, acc10, 0, 0, 0);
        acc11 = __builtin_amdgcn_mfma_f32_16x16x32_f16(a1, b1, acc11, 0, 0, 0);
        if (kt + 1 < kIters) {
            *(uint4*)&lsA[cur ^ 1][stOff] = va;
            *(uint4*)&lsW[cur ^ 1][stOff] = vw;
            if (kt + 2 < kIters) {
                va = *(const uint4*)gA; vw = *(const uint4*)gW;
                gA += 32; gW += 32;
            }
            __syncthreads();
        }
        cur ^= 1;
    }

    int side = (twoSided && r0 >= 1024) ? 1 : 0;
    int gc0 = c0 + waveC * 32 + m;
    int gc1 = gc0 + 16;
    float bias0 = (gc0 < N) ? bias[gc0] : 0.f;
    float bias1 = (gc1 < N) ? bias[gc1] : 0.f;
    float colS0 = 0.f, colQ0 = 0.f, colS1 = 0.f, colQ1 = 0.f;
    #pragma unroll
    for (int i = 0; i < 2; i++) {
        f32x4 cv0 = i ? acc10 : acc00;
        f32x4 cv1 = i ? acc11 : acc01;
        #pragma unroll
        for (int r = 0; r < 4; r++) {
            int gr = r0 + waveR * 32 + i * 16 + q * 4 + r;
            if (gc0 < N) {
                float v = cv0[r] + bias0;
                C[(size_t)gr * ldc + gc0] = v;
                colS0 += v; colQ0 += v * v;
            }
            if (gc1 < N) {
                float v = cv1[r] + bias1;
                C[(size_t)gr * ldc + gc1] = v;
                colS1 += v; colQ1 += v * v;
            }
        }
    }
    colS0 += __shfl_down(colS0, 32); colS0 += __shfl_down(colS0, 16);
    colQ0 += __shfl_down(colQ0, 32); colQ0 += __shfl_down(colQ0, 16);
    colS1 += __shfl_down(colS1, 32); colS1 += __shfl_down(colS1, 16);
    colQ1 += __shfl_down(colQ1, 32); colQ1 += __shfl_down(colQ1, 16);
    if (q == 0) {
        if (gc0 < N) {
            atomicAdd(&sSum[side * N + gc0], colS0);
            atomicAdd(&sSq[side * N + gc0], colQ0);
        }
        if (gc1 < N) {
            atomicAdd(&sSum[side * N + gc1], colS1);
            atomicAdd(&sSq[side * N + gc1], colQ1);
        }
    }
}

// ---------------------------------------------------------------------------
// MFMA GEMM with fused BN+ReLU+f16-convert on the A operand:
// A_eff[r][c] = relu((Z[r][c] - mean_c) * rsqrt(var_c + EPS)) for c < kValid,
// 0 otherwise (K zero-pad), with per-side stats when bnTwoSided.
// Same tile/pipeline structure as gemm_f16.
// ---------------------------------------------------------------------------
__global__ __launch_bounds__(256) void gemm_bnA(
    const float* __restrict__ Z, int ldz, int kValid,
    const float* __restrict__ bnS, const float* __restrict__ bnQ, int bnTwoSided,
    const _Float16* __restrict__ W, int ldk,
    const float* __restrict__ bias, float* __restrict__ C, int ldc,
    int N, int kIters, float* __restrict__ sSum, float* __restrict__ sSq,
    int twoSided)
{
    __shared__ __align__(16) _Float16 lsA[2][2048];
    __shared__ __align__(16) _Float16 lsW[2][2048];
    int tid = threadIdx.x;
    int r0 = blockIdx.x * 64, c0 = blockIdx.y * 64;
    int lane = tid & 63;
    int wave = tid >> 6;
    int waveR = wave & 1, waveC = wave >> 1;
    int q = lane >> 4, m = lane & 15;

    int srow = tid >> 2, sseg = tid & 3;
    int bnSide = (bnTwoSided && r0 >= 1024) ? 1 : 0;
    const float* bS = bnS + bnSide * kValid;
    const float* bQ = bnQ + bnSide * kValid;
    const float* gZ = Z + (size_t)(r0 + srow) * ldz + sseg * 8;
    const _Float16* gW = W + (size_t)(c0 + srow) * ldk + sseg * 8;
    int stOff = sseg * 512 + srow * 8;

    int aoff0 = q * 512 + (waveR * 32 + m) * 8;
    int aoff1 = aoff0 + 128;
    int boff0 = q * 512 + (waveC * 32 + m) * 8;
    int boff1 = boff0 + 128;

    f32x4 acc00 = {0.f,0.f,0.f,0.f}, acc01 = {0.f,0.f,0.f,0.f};
    f32x4 acc10 = {0.f,0.f,0.f,0.f}, acc11 = {0.f,0.f,0.f,0.f};

    // prefetch state: raw Z (2xfloat4), stats (4xfloat4), W (uint4)
    float4 z0, z1, s0, s1, u0, u1;
    uint4 vw;
    int kcol = sseg * 8;   // column base of this thread's 8-wide slab

    // load kt
    #define LOAD_BNA(kt_) do {                                             \
        int cb = (kt_) * 32 + kcol;                                        \
        z0 = *(const float4*)(gZ + (kt_) * 32);                            \
        z1 = *(const float4*)(gZ + (kt_) * 32 + 4);                        \
        s0 = *(const float4*)(bS + cb);                                    \
        s1 = *(const float4*)(bS + cb + 4);                                \
        u0 = *(const float4*)(bQ + cb);                                    \
        u1 = *(const float4*)(bQ + cb + 4);                                \
        vw = *(const uint4*)(gW + (size_t)(kt_) * 32);                     \
    } while (0)

    // consume prefetched regs -> BN -> f16 -> LDS buf
    #define STORE_BNA(buf_, kt_) do {                                      \
        int cb = (kt_) * 32 + kcol;                                        \
        f16x8 h;                                                           \
        _Pragma("unroll")                                                  \
        for (int j = 0; j < 8; j++) {                                      \
            int c = cb + j;                                                \
            float v = 0.f;                                                 \
            if (c < kValid) {                                              \
                float sv = (j < 4) ? ((const float*)&s0)[j]                \
                                   : ((const float*)&s1)[j - 4];           \
                float qv = (j < 4) ? ((const float*)&u0)[j]                \
                                   : ((const float*)&u1)[j - 4];           \
                float zv = (j < 4) ? ((const float*)&z0)[j]                \
                                   : ((const float*)&z1)[j - 4];           \
                float mean = sv * INV_N;                                   \
                float var  = qv * INV_N - mean * mean;                     \
                v = fmaxf((zv - mean) * rsqrtf(var + EPS), 0.f);           \
            }                                                              \
            h[j] = f2h(v);                                                 \
        }                                                                  \
        *(f16x8*)&lsA[buf_][stOff] = h;                                    \
        *(uint4*)&lsW[buf_][stOff] = vw;                                   \
    } while (0)

    // prologue: stage kt=0, prefetch kt=1
    LOAD_BNA(0);
    STORE_BNA(0, 0);
    if (kIters > 1) LOAD_BNA(1);
    __syncthreads();

    int cur = 0;
    for (int kt = 0; kt < kIters; kt++) {
        f16x8 a0 = *(const f16x8*)&lsA[cur][aoff0];
        f16x8 a1 = *(const f16x8*)&lsA[cur][aoff1];
        f16x8 b0 = *(const f16x8*)&lsW[cur][boff0];
        f16x8 b1 = *(const f16x8*)&lsW[cur][boff1];
        acc00 = __builtin_amdgcn_mfma_f32_16x16x32_f16(a0, b0, acc00, 0, 0, 0);
        acc01 = __builtin_amdgcn_mfma_f32_16x16x32_f16(a0, b1, acc01, 0, 0, 0);
        acc10 = __builtin_amdgcn_mfma_f32_16x16x32_f16(a1, b0, acc10, 0, 0, 0);
        acc11 = __builtin_amdgcn_mfma_f32_16x16x32_f16(a1, b1, acc11, 0, 0, 0);
        if (kt + 1 < kIters) {
            STORE_BNA(cur ^ 1, kt + 1);
            if (kt + 2 < kIters) LOAD_BNA(kt + 2);
            __syncthreads();
        }
        cur ^= 1;
    }
    #undef LOAD_BNA
    #undef STORE_BNA

    int side = (twoSided && r0 >= 1024) ? 1 : 0;
    int gc0 = c0 + waveC * 32 + m;
    int gc1 = gc0 + 16;
    float bias0 = (gc0 < N) ? bias[gc0] : 0.f;
    float bias1 = (gc1 < N) ? bias[gc1] : 0.f;
    float colS0 = 0.f, colQ0 = 0.f, colS1 = 0.f, colQ1 = 0.f;
    #pragma unroll
    for (int i = 0; i < 2; i++) {
        f32x4 cv0 = i ? acc10 : acc00;
        f32x4 cv1 = i ? acc11 : acc01;
        #pragma unroll
        for (int r = 0; r < 4; r++) {
            int gr = r0 + waveR * 32 + i * 16 + q * 4 + r;
            if (gc0 < N) {
                float v = cv0[r] + bias0;
                C[(size_t)gr * ldc + gc0] = v;
                colS0 += v; colQ0 += v * v;
            }
            if (gc1 < N) {
                float v = cv1[r] + bias1;
                C[(size_t)gr * ldc + gc1] = v;
                colS1 += v; colQ1 += v * v;
            }
        }
    }
    colS0 += __shfl_down(colS0, 32); colS0 += __shfl_down(colS0, 16);
    colQ0 += __shfl_down(colQ0, 32); colQ0 += __shfl_down(colQ0, 16);
    colS1 += __shfl_down(colS1, 32); colS1 += __shfl_down(colS1, 16);
    colQ1 += __shfl_down(colQ1, 32); colQ1 += __shfl_down(colQ1, 16);
    if (q == 0) {
        if (gc0 < N) {
            atomicAdd(&sSum[side * N + gc0], colS0);
            atomicAdd(&sSq[side * N + gc0], colQ0);
        }
        if (gc1 < N) {
            atomicAdd(&sSum[side * N + gc1], colS1);
            atomicAdd(&sSq[side * N + gc1], colQ1);
        }
    }
}

// ---------------------------------------------------------------------------
// BN2+ReLU -> o1,o2 (fp32 to d_out), nxt f16 [1024][928] padded.
// ---------------------------------------------------------------------------
__global__ __launch_bounds__(128) void pair_kernel(
    const float* __restrict__ z2, const float* __restrict__ sS,
    const float* __restrict__ sQ, float* __restrict__ out,
    _Float16* __restrict__ nxtb)
{
    int b = blockIdx.x, t = threadIdx.x;
    __shared__ float red[128];
    float dot = 0.f;
    for (int d = t; d < 300; d += 128) {
        float m1 = sS[d] * INV_N;
        float v1 = sQ[d] * INV_N - m1 * m1;
        float m2 = sS[300 + d] * INV_N;
        float v2 = sQ[300 + d] * INV_N - m2 * m2;
        float a1 = fmaxf((z2[(size_t)b * 300 + d] - m1) * rsqrtf(v1 + EPS), 0.f);
        float a2 = fmaxf((z2[(size_t)(1024 + b) * 300 + d] - m2) * rsqrtf(v2 + EPS), 0.f);
        out[1024 + (size_t)b * 300 + d] = a1;
        out[308224 + (size_t)b * 300 + d] = a2;
        nxtb[(size_t)b * 928 + d] = f2h(a1);
        nxtb[(size_t)b * 928 + 300 + d] = f2h(a2);
        nxtb[(size_t)b * 928 + 600 + d] = f2h(fabsf(a1 - a2));
        dot += a1 * a2;
    }
    red[t] = dot;
    __syncthreads();
    if (t < 27) nxtb[(size_t)b * 928 + 901 + t] = (_Float16)0.f;
    if (t == 0) {
        float s = 0.f;
        for (int i = 0; i < 128; i++) s += red[i];
        nxtb[(size_t)b * 928 + 900] = f2h(s);
    }
}

// ---------------------------------------------------------------------------
// final: BN4+ReLU, dot w5, sigmoid -> prob. grid 1024, block 64.
// ---------------------------------------------------------------------------
__global__ __launch_bounds__(64) void final_kernel(
    const float* __restrict__ y4, const float* __restrict__ sS,
    const float* __restrict__ sQ, const float* __restrict__ w5,
    const float* __restrict__ b5, float* __restrict__ out)
{
    int b = blockIdx.x, l = threadIdx.x;
    float acc = 0.f;
    for (int j = l; j < 100; j += 64) {
        float mean = sS[j] * INV_N;
        float var = sQ[j] * INV_N - mean * mean;
        float v = (y4[(size_t)b * 100 + j] - mean) * rsqrtf(var + EPS);
        v = v > 0.f ? v : 0.f;
        acc += v * w5[j];
    }
    #pragma unroll
    for (int off = 32; off; off >>= 1) acc += __shfl_down(acc, off);
    if (l == 0) out[b] = 1.f / (1.f + expf(-(acc + b5[0])));
}

// ---------------------------------------------------------------------------
extern "C" void kernel_launch(void* const* d_in, const int* in_sizes, int n_in,
                              void* d_out, int out_size, void* d_ws, size_t ws_size,
                              hipStream_t stream)
{
    const int* langs1 = (const int*)d_in[0];
    const int* sents1 = (const int*)d_in[1];
    const int* langs2 = (const int*)d_in[2];
    const int* sents2 = (const int*)d_in[3];
    const float* tables = (const float*)d_in[4];
    const float* w1 = (const float*)d_in[5];
    const float* b1 = (const float*)d_in[6];
    const float* w2 = (const float*)d_in[7];
    const float* b2 = (const float*)d_in[8];
    const float* w3 = (const float*)d_in[9];
    const float* b3 = (const float*)d_in[10];
    const float* w4 = (const float*)d_in[11];
    const float* b4 = (const float*)d_in[12];
    const float* w5 = (const float*)d_in[13];
    const float* b5 = (const float*)d_in[14];

    float* ws = (float*)d_ws;
    float* F0 = ws;
    float* F1 = ws + 614400;
    float* stats = ws + 1228800;
    float* s1S = stats;        float* s1Q = stats + 600;
    float* s2S = stats + 1200; float* s2Q = stats + 1800;
    float* s3S = stats + 2400; float* s3Q = stats + 2800;
    float* s4S = stats + 3200; float* s4Q = stats + 3300;
    _Float16* hb = (_Float16*)(ws + 1232208);
    _Float16* xb   = hb;
    _Float16* nxtb = hb + 1310720;
    _Float16* w1b  = hb + 2686976;
    _Float16* w2b  = hb + 2789376;
    _Float16* w3b  = hb + 2891776;
    _Float16* w4b  = hb + 3307520;

    float* out = (float*)d_out;

    // K1: gather (2048 blocks) + weight cvt (1316 blocks)
    gather_wcvt_kernel<<<3364, 128, 0, stream>>>(
        langs1, sents1, langs2, sents2, tables, xb, stats,
        w1, w2, w3, w4, w1b, w2b, w3b, w4b);
    // z1 = xb @ w1^T + b1  (stats1, two-sided)
    gemm_f16<<<dim3(32, 5), 256, 0, stream>>>(xb, w1b, 320, b1, F0, 300,
                                              300, 10, s1S, s1Q, 1);
    // z2 = BN1(z1).relu @ w2^T + b2  (BN fused into A-staging; stats2 two-sided)
    gemm_bnA<<<dim3(32, 5), 256, 0, stream>>>(F0, 300, 300, s1S, s1Q, 1,
                                              w2b, 320, b2, F1, 300,
                                              300, 10, s2S, s2Q, 1);
    // o1,o2,nxt from z2 + stats2
    pair_kernel<<<1024, 128, 0, stream>>>(F1, s2S, s2Q, out, nxtb);
    // z3 = nxt @ w3^T + b3  (stats3)
    gemm_f16<<<dim3(16, 7), 256, 0, stream>>>(nxtb, w3b, 928, b3, F0, 400,
                                              400, 29, s3S, s3Q, 0);
    // z4 = BN3(z3).relu @ w4^T + b4  (BN fused; stats4)
    gemm_bnA<<<dim3(16, 2), 256, 0, stream>>>(F0, 400, 400, s3S, s3Q, 0,
                                              w4b, 416, b4, F1, 100,
                                              100, 13, s4S, s4Q, 0);
    // prob
    final_kernel<<<1024, 64, 0, stream>>>(F1, s4S, s4Q, w5, b5, out);
}